// Round 3
// baseline (235.011 us; speedup 1.0000x reference)
//
#include <hip/hip_runtime.h>
#include <hip/hip_bf16.h>
#include <cstdint>
#include <cstddef>

#define DD 768
#define TSCALE 20.0f

typedef short bf16x8 __attribute__((ext_vector_type(8)));
typedef float f32x4 __attribute__((ext_vector_type(4)));

__device__ inline float wsum(float v){
  #pragma unroll
  for (int m = 1; m < 64; m <<= 1) v += __shfl_xor(v, m, 64);
  return v;
}
__device__ inline float wmax(float v){
  #pragma unroll
  for (int m = 1; m < 64; m <<= 1) v = fmaxf(v, __shfl_xor(v, m, 64));
  return v;
}

__device__ inline void gload_lds16(const void* g, void* l){
  __builtin_amdgcn_global_load_lds(
      (const __attribute__((address_space(1))) uint32_t*)g,
      (__attribute__((address_space(3))) uint32_t*)l, 16, 0, 0);
}

// Normalize rows: obj (8*NB), arg slots {0,2,3} (3*NB), text slot 1 (NB).
__global__ __launch_bounds__(64) void norm_rows(
    const float* __restrict__ obj, const float* __restrict__ txt,
    float* __restrict__ objn, float* __restrict__ argn, float* __restrict__ t1n,
    __hip_bfloat16* __restrict__ objb, __hip_bfloat16* __restrict__ argb, int NB)
{
  int row = blockIdx.x, lane = threadIdx.x;
  int NO = NB * 8, NA = NB * 3;
  const float* src; float* dst; __hip_bfloat16* bdst = nullptr;
  if (row < NO) {
    src = obj + (size_t)row * DD; dst = objn + (size_t)row * DD; bdst = objb + (size_t)row * DD;
  } else if (row < NO + NA) {
    int r = row - NO; int i = r / 3, j = r - i * 3; int s = (j == 0) ? 0 : (j + 1);
    src = txt + ((size_t)i * 4 + s) * DD; dst = argn + (size_t)r * DD; bdst = argb + (size_t)r * DD;
  } else {
    int i = row - NO - NA;
    src = txt + ((size_t)i * 4 + 1) * DD; dst = t1n + (size_t)i * DD;
  }
  float v[12]; float ss = 0.f;
  #pragma unroll
  for (int q = 0; q < 12; ++q){ v[q] = src[lane + q * 64]; ss += v[q] * v[q]; }
  ss = wsum(ss);
  float inv = 1.0f / fmaxf(sqrtf(ss), 1e-12f);
  #pragma unroll
  for (int q = 0; q < 12; ++q){
    float x = v[q] * inv;
    dst[lane + q * 64] = x;
    if (bdst) bdst[lane + q * 64] = __float2bfloat16(x);
  }
}

// ===================== wpg GEMM: 256x256 tile, BK=64, 8-phase =====================
// A = argb [3840, 768], B = objb [10240, 768] (both row-major bf16, K-contig).
// Fused epilogue: sumexp[row] += sum_col exp(20*c - 20).
// LDS 128 KiB: [buf(2)][mat(2)][half(2)] of 16 KiB (128 rows x 64 cols bf16, linear).
#define LDSOFF(buf, mat, half) (((buf) << 16) + ((mat) << 15) + ((half) << 14))

__global__ __launch_bounds__(512, 2) void wpg_gemm_256(
    const __hip_bfloat16* __restrict__ A, const __hip_bfloat16* __restrict__ B,
    float* __restrict__ sumexp)
{
  __shared__ char lds[131072];
  const int tid = threadIdx.x;
  const int lane = tid & 63, wid = tid >> 6;
  const int wr = wid >> 2, wc = wid & 3;          // 2 x 4 waves
  const int r = lane & 15, kg = lane >> 4;        // frag row / k-group

  const char* Abase = (const char*)A + (size_t)blockIdx.y * 256 * (DD * 2);
  const char* Bbase = (const char*)B + (size_t)blockIdx.x * 256 * (DD * 2);

  const int c0 = tid, c1 = tid + 512;             // 16B chunks of a 16 KiB half-tile

  auto STAGE = [&](const char* gbase, int buf, int mat, int half, int kt){
    const char* g0 = gbase + (size_t)(half * 128 + (c0 >> 3)) * (DD * 2) + kt * 128 + (c0 & 7) * 16;
    const char* g1 = gbase + (size_t)(half * 128 + (c1 >> 3)) * (DD * 2) + kt * 128 + (c1 & 7) * 16;
    gload_lds16(g0, lds + LDSOFF(buf, mat, half) + c0 * 16);
    gload_lds16(g1, lds + LDSOFF(buf, mat, half) + c1 * 16);
  };
  // A frag: rows wr*128 + mi*16 + r (within half 'wr'), k = kk*32 + kg*8
  auto LDA = [&](int buf, int mi, int kk)->bf16x8 {
    return *(const bf16x8*)(lds + LDSOFF(buf, 0, wr) + (mi * 16 + r) * 128 + kk * 64 + kg * 16);
  };
  // B frag: cols wc*64 + ni*16 + r (half = wc>>1, row-in-half = (wc&1)*64 + ni*16 + r)
  auto LDB = [&](int buf, int ni, int kk)->bf16x8 {
    return *(const bf16x8*)(lds + LDSOFF(buf, 1, wc >> 1) + ((wc & 1) * 64 + ni * 16 + r) * 128 + kk * 64 + kg * 16);
  };

  f32x4 acc[8][4];
  #pragma unroll
  for (int i = 0; i < 8; ++i)
    #pragma unroll
    for (int j = 0; j < 4; ++j) acc[i][j] = (f32x4){0.f, 0.f, 0.f, 0.f};

  bf16x8 a[4][2], b0[2][2], b1[2][2];

  // Prologue: tile0 (full, buf0) + tile1 B halves (buf1). 12 loads/wave.
  STAGE(Bbase, 0, 1, 0, 0); STAGE(Bbase, 0, 1, 1, 0);
  STAGE(Abase, 0, 0, 0, 0); STAGE(Abase, 0, 0, 1, 0);
  STAGE(Bbase, 1, 1, 0, 1); STAGE(Bbase, 1, 1, 1, 1);
  asm volatile("s_waitcnt vmcnt(4)" ::: "memory");
  __builtin_amdgcn_s_barrier();
  __builtin_amdgcn_sched_barrier(0);

  #define MFMA_(d, av, bv) d = __builtin_amdgcn_mfma_f32_16x16x32_bf16(av, bv, d, 0, 0, 0)

  for (int it = 0; it < 6; ++it){
    const int t1 = 2 * it + 1;
    const int t2 = (2 * it + 2 < 11) ? 2 * it + 2 : 11;
    const int t3 = (2 * it + 3 < 11) ? 2 * it + 3 : 11;

    // ---- P0: buf0, quad(mi0-3, ni0-1). stage A-h0(t1)->buf1
    #pragma unroll
    for (int mi = 0; mi < 4; ++mi){ a[mi][0] = LDA(0, mi, 0); a[mi][1] = LDA(0, mi, 1); }
    #pragma unroll
    for (int ni = 0; ni < 2; ++ni){ b0[ni][0] = LDB(0, ni, 0); b0[ni][1] = LDB(0, ni, 1); }
    STAGE(Abase, 1, 0, 0, t1);
    __builtin_amdgcn_s_barrier();
    __builtin_amdgcn_s_setprio(1);
    #pragma unroll
    for (int mi = 0; mi < 4; ++mi)
      #pragma unroll
      for (int ni = 0; ni < 2; ++ni){ MFMA_(acc[mi][ni], a[mi][0], b0[ni][0]); MFMA_(acc[mi][ni], a[mi][1], b0[ni][1]); }
    __builtin_amdgcn_s_setprio(0);
    __builtin_amdgcn_s_barrier();

    // ---- P1: buf0, quad(mi0-3, ni2-3). stage A-h1(t1)->buf1
    #pragma unroll
    for (int ni = 0; ni < 2; ++ni){ b1[ni][0] = LDB(0, 2 + ni, 0); b1[ni][1] = LDB(0, 2 + ni, 1); }
    STAGE(Abase, 1, 0, 1, t1);
    __builtin_amdgcn_s_barrier();
    __builtin_amdgcn_s_setprio(1);
    #pragma unroll
    for (int mi = 0; mi < 4; ++mi)
      #pragma unroll
      for (int ni = 0; ni < 2; ++ni){ MFMA_(acc[mi][2 + ni], a[mi][0], b1[ni][0]); MFMA_(acc[mi][2 + ni], a[mi][1], b1[ni][1]); }
    __builtin_amdgcn_s_setprio(0);
    __builtin_amdgcn_s_barrier();

    // ---- P2: buf0, quad(mi4-7, ni2-3). stage B-h0(t2)->buf0
    #pragma unroll
    for (int mi = 0; mi < 4; ++mi){ a[mi][0] = LDA(0, 4 + mi, 0); a[mi][1] = LDA(0, 4 + mi, 1); }
    STAGE(Bbase, 0, 1, 0, t2);
    __builtin_amdgcn_s_barrier();
    __builtin_amdgcn_s_setprio(1);
    #pragma unroll
    for (int mi = 0; mi < 4; ++mi)
      #pragma unroll
      for (int ni = 0; ni < 2; ++ni){ MFMA_(acc[4 + mi][2 + ni], a[mi][0], b1[ni][0]); MFMA_(acc[4 + mi][2 + ni], a[mi][1], b1[ni][1]); }
    __builtin_amdgcn_s_setprio(0);
    __builtin_amdgcn_s_barrier();

    // ---- P3: buf0, quad(mi4-7, ni0-1). stage B-h1(t2)->buf0. vmcnt gate for buf1 reads.
    STAGE(Bbase, 0, 1, 1, t2);
    __builtin_amdgcn_s_barrier();
    __builtin_amdgcn_s_setprio(1);
    #pragma unroll
    for (int mi = 0; mi < 4; ++mi)
      #pragma unroll
      for (int ni = 0; ni < 2; ++ni){ MFMA_(acc[4 + mi][ni], a[mi][0], b0[ni][0]); MFMA_(acc[4 + mi][ni], a[mi][1], b0[ni][1]); }
    __builtin_amdgcn_s_setprio(0);
    asm volatile("s_waitcnt vmcnt(4)" ::: "memory");
    __builtin_amdgcn_s_barrier();
    __builtin_amdgcn_sched_barrier(0);

    // ---- P4: buf1, quad(mi0-3, ni0-1). stage A-h0(t2)->buf0
    #pragma unroll
    for (int mi = 0; mi < 4; ++mi){ a[mi][0] = LDA(1, mi, 0); a[mi][1] = LDA(1, mi, 1); }
    #pragma unroll
    for (int ni = 0; ni < 2; ++ni){ b0[ni][0] = LDB(1, ni, 0); b0[ni][1] = LDB(1, ni, 1); }
    STAGE(Abase, 0, 0, 0, t2);
    __builtin_amdgcn_s_barrier();
    __builtin_amdgcn_s_setprio(1);
    #pragma unroll
    for (int mi = 0; mi < 4; ++mi)
      #pragma unroll
      for (int ni = 0; ni < 2; ++ni){ MFMA_(acc[mi][ni], a[mi][0], b0[ni][0]); MFMA_(acc[mi][ni], a[mi][1], b0[ni][1]); }
    __builtin_amdgcn_s_setprio(0);
    __builtin_amdgcn_s_barrier();

    // ---- P5: buf1, quad(mi0-3, ni2-3). stage A-h1(t2)->buf0
    #pragma unroll
    for (int ni = 0; ni < 2; ++ni){ b1[ni][0] = LDB(1, 2 + ni, 0); b1[ni][1] = LDB(1, 2 + ni, 1); }
    STAGE(Abase, 0, 0, 1, t2);
    __builtin_amdgcn_s_barrier();
    __builtin_amdgcn_s_setprio(1);
    #pragma unroll
    for (int mi = 0; mi < 4; ++mi)
      #pragma unroll
      for (int ni = 0; ni < 2; ++ni){ MFMA_(acc[mi][2 + ni], a[mi][0], b1[ni][0]); MFMA_(acc[mi][2 + ni], a[mi][1], b1[ni][1]); }
    __builtin_amdgcn_s_setprio(0);
    __builtin_amdgcn_s_barrier();

    // ---- P6: buf1, quad(mi4-7, ni2-3). stage B-h0(t3)->buf1
    #pragma unroll
    for (int mi = 0; mi < 4; ++mi){ a[mi][0] = LDA(1, 4 + mi, 0); a[mi][1] = LDA(1, 4 + mi, 1); }
    STAGE(Bbase, 1, 1, 0, t3);
    __builtin_amdgcn_s_barrier();
    __builtin_amdgcn_s_setprio(1);
    #pragma unroll
    for (int mi = 0; mi < 4; ++mi)
      #pragma unroll
      for (int ni = 0; ni < 2; ++ni){ MFMA_(acc[4 + mi][2 + ni], a[mi][0], b1[ni][0]); MFMA_(acc[4 + mi][2 + ni], a[mi][1], b1[ni][1]); }
    __builtin_amdgcn_s_setprio(0);
    __builtin_amdgcn_s_barrier();

    // ---- P7: buf1, quad(mi4-7, ni0-1). stage B-h1(t3)->buf1. vmcnt gate for next buf0 reads.
    STAGE(Bbase, 1, 1, 1, t3);
    __builtin_amdgcn_s_barrier();
    __builtin_amdgcn_s_setprio(1);
    #pragma unroll
    for (int mi = 0; mi < 4; ++mi)
      #pragma unroll
      for (int ni = 0; ni < 2; ++ni){ MFMA_(acc[4 + mi][ni], a[mi][0], b0[ni][0]); MFMA_(acc[4 + mi][ni], a[mi][1], b0[ni][1]); }
    __builtin_amdgcn_s_setprio(0);
    asm volatile("s_waitcnt vmcnt(4)" ::: "memory");
    __builtin_amdgcn_s_barrier();
    __builtin_amdgcn_sched_barrier(0);
  }

  // Epilogue: per-row sum of exp(20c-20). C layout: col = lane&15, row = kg*4 + reg.
  const int rowbase = blockIdx.y * 256 + wr * 128 + kg * 4;
  #pragma unroll
  for (int mi = 0; mi < 8; ++mi){
    #pragma unroll
    for (int rr = 0; rr < 4; ++rr){
      float s = 0.f;
      #pragma unroll
      for (int ni = 0; ni < 4; ++ni) s += expf(fmaf(acc[mi][ni][rr], TSCALE, -TSCALE));
      s += __shfl_xor(s, 1, 64); s += __shfl_xor(s, 2, 64);
      s += __shfl_xor(s, 4, 64); s += __shfl_xor(s, 8, 64);
      if (r == 0) atomicAdd(&sumexp[rowbase + mi * 16 + rr], s);
    }
  }
}

// =========== fused diag (exact fp32 argmax/mask) + te/ve assembly ===========
__global__ __launch_bounds__(64) void diag_teve(
    const float* __restrict__ argn, const float* __restrict__ objn, const float* __restrict__ t1n,
    float* __restrict__ diagmax,
    __hip_bfloat16* __restrict__ tenb, __hip_bfloat16* __restrict__ venb)
{
  int i = blockIdx.x, lane = threadIdx.x;
  float te[12], ve[12];
  #pragma unroll
  for (int q = 0; q < 12; ++q){ te[q] = t1n[(size_t)i * DD + lane + q * 64]; ve[q] = 0.f; }

  for (int j = 0; j < 3; ++j){
    int rr = i * 3 + j;
    float a[12];
    #pragma unroll
    for (int q = 0; q < 12; ++q) a[q] = argn[(size_t)rr * DD + lane + q * 64];
    float best = -3.0e38f; int bi = 0;
    for (int k = 0; k < 8; ++k){
      const float* o = objn + (size_t)(i * 8 + k) * DD;
      float s = 0.f;
      #pragma unroll
      for (int q = 0; q < 12; ++q) s += a[q] * o[lane + q * 64];
      s = wsum(s);
      if (s > best){ best = s; bi = k; }   // strict > == first-index tie rule
    }
    float dm = best * TSCALE;
    if (lane == 0) diagmax[rr] = dm;
    if (dm > 1.0f){                         // uniform across wave (wsum broadcast)
      const float* op = objn + (size_t)(i * 8 + bi) * DD;
      #pragma unroll
      for (int q = 0; q < 12; ++q){ te[q] += a[q]; ve[q] += op[lane + q * 64]; }
    }
  }
  float ss = 0.f;
  #pragma unroll
  for (int q = 0; q < 12; ++q) ss += te[q] * te[q];
  ss = wsum(ss);
  float inv = 1.0f / fmaxf(sqrtf(ss), 1e-12f);
  #pragma unroll
  for (int q = 0; q < 12; ++q) tenb[(size_t)i * DD + lane + q * 64] = __float2bfloat16(te[q] * inv);
  ss = 0.f;
  #pragma unroll
  for (int q = 0; q < 12; ++q) ss += ve[q] * ve[q];
  ss = wsum(ss);
  inv = 1.0f / fmaxf(sqrtf(ss), 1e-12f);
  #pragma unroll
  for (int q = 0; q < 12; ++q) venb[(size_t)i * DD + lane + q * 64] = __float2bfloat16(ve[q] * inv);
}

// ec: A=tenb, B=venb [NB,768]; fused row/col exp-sums + diag capture (128^2 m97 structure).
__global__ __launch_bounds__(256) void ec_gemm_mfma(
    const __hip_bfloat16* __restrict__ A, const __hip_bfloat16* __restrict__ B,
    float* __restrict__ rowsum, float* __restrict__ colsum, float* __restrict__ Ldiag)
{
  __shared__ __hip_bfloat16 As[128 * 32];
  __shared__ __hip_bfloat16 Bs[128 * 32];
  int tid = threadIdx.x;
  int bx = blockIdx.x, by = blockIdx.y;
  int wid = tid >> 6, lane = tid & 63;
  int wr = wid >> 1, wc = wid & 1;

  f32x4 acc[4][4];
  #pragma unroll
  for (int i = 0; i < 4; ++i)
    #pragma unroll
    for (int j = 0; j < 4; ++j) acc[i][j] = (f32x4){0.f, 0.f, 0.f, 0.f};

  const char* Ab = (const char*)(A + (size_t)(by * 128) * DD);
  const char* Bb = (const char*)(B + (size_t)(bx * 128) * DD);
  int srow = tid >> 2;
  int scol = (tid & 3) * 16;
  char* AsB = (char*)As; char* BsB = (char*)Bs;
  int r = lane & 15, kg = (lane >> 4) * 8;

  for (int kb = 0; kb < DD * 2; kb += 64){
    gload_lds16(Ab + (size_t)srow * (DD*2) + kb + scol, AsB + tid * 16);
    gload_lds16(Ab + (size_t)(srow + 64) * (DD*2) + kb + scol, AsB + 4096 + tid * 16);
    gload_lds16(Bb + (size_t)srow * (DD*2) + kb + scol, BsB + tid * 16);
    gload_lds16(Bb + (size_t)(srow + 64) * (DD*2) + kb + scol, BsB + 4096 + tid * 16);
    __syncthreads();
    bf16x8 af[4], bfr[4];
    #pragma unroll
    for (int mi = 0; mi < 4; ++mi)
      af[mi] = *(const bf16x8*)&As[(wr * 64 + mi * 16 + r) * 32 + kg];
    #pragma unroll
    for (int ni = 0; ni < 4; ++ni)
      bfr[ni] = *(const bf16x8*)&Bs[(wc * 64 + ni * 16 + r) * 32 + kg];
    #pragma unroll
    for (int mi = 0; mi < 4; ++mi)
      #pragma unroll
      for (int ni = 0; ni < 4; ++ni)
        acc[mi][ni] = __builtin_amdgcn_mfma_f32_16x16x32_bf16(af[mi], bfr[ni], acc[mi][ni], 0, 0, 0);
    __syncthreads();
  }
  int rowbase = by * 128 + wr * 64 + ((lane >> 4) << 2);
  float colacc[4] = {0.f, 0.f, 0.f, 0.f};
  #pragma unroll
  for (int mi = 0; mi < 4; ++mi){
    #pragma unroll
    for (int rr = 0; rr < 4; ++rr){
      float s = 0.f;
      #pragma unroll
      for (int ni = 0; ni < 4; ++ni){
        float e = expf(fmaf(acc[mi][ni][rr], TSCALE, -TSCALE));
        s += e; colacc[ni] += e;
      }
      s += __shfl_xor(s, 1, 64); s += __shfl_xor(s, 2, 64);
      s += __shfl_xor(s, 4, 64); s += __shfl_xor(s, 8, 64);
      if ((lane & 15) == 0) atomicAdd(&rowsum[rowbase + mi * 16 + rr], s);
    }
  }
  #pragma unroll
  for (int ni = 0; ni < 4; ++ni){
    float c = colacc[ni];
    c += __shfl_xor(c, 16, 64); c += __shfl_xor(c, 32, 64);
    if (lane < 16) atomicAdd(&colsum[bx * 128 + wc * 64 + ni * 16 + lane], c);
  }
  if (bx == by){
    #pragma unroll
    for (int mi = 0; mi < 4; ++mi)
      #pragma unroll
      for (int ni = 0; ni < 4; ++ni)
        #pragma unroll
        for (int rr = 0; rr < 4; ++rr){
          int grow = wr * 64 + mi * 16 + ((lane >> 4) << 2) + rr;
          int gcol = wc * 64 + ni * 16 + (lane & 15);
          if (grow == gcol) Ldiag[by * 128 + grow] = acc[mi][ni][rr] * TSCALE;
        }
  }
}

__global__ __launch_bounds__(64) void lossv_kernel(
    const float* __restrict__ mdl, const int* __restrict__ lab,
    float* __restrict__ acc, int C)
{
  int row = blockIdx.x, lane = threadIdx.x;
  const float* x = mdl + (size_t)row * C;
  float mx = -3.0e38f;
  for (int c = lane; c < C; c += 64) mx = fmaxf(mx, x[c]);
  mx = wmax(mx);
  float s = 0.f;
  for (int c = lane; c < C; c += 64) s += expf(x[c] - mx);
  s = wsum(s);
  if (lane == 0) atomicAdd(acc, logf(s) + mx - x[lab[row]]);
}

__global__ __launch_bounds__(256) void finalize_kernel(
    const float* __restrict__ sumexp, const float* __restrict__ diagmax,
    const float* __restrict__ rowsum, const float* __restrict__ colsum,
    const float* __restrict__ Ldiag, const float* __restrict__ lossv,
    float* __restrict__ out, int NB)
{
  int tid = threadIdx.x;
  float p = 0.f;
  for (int r = tid; r < 3 * NB; r += 256) p += logf(sumexp[r]) + TSCALE - diagmax[r];
  p *= (0.3f / (3.0f * NB));
  float q = 0.f;
  for (int i2 = tid; i2 < NB; i2 += 256)
    q += (logf(rowsum[i2]) + TSCALE - Ldiag[i2]) + (logf(colsum[i2]) + TSCALE - Ldiag[i2]);
  p += q * (0.25f / NB);
  __shared__ float red[256];
  red[tid] = p; __syncthreads();
  for (int s = 128; s > 0; s >>= 1){ if (tid < s) red[tid] += red[tid + s]; __syncthreads(); }
  if (tid == 0) out[0] = red[0] + 0.2f * (lossv[0] / NB);
}

extern "C" void kernel_launch(void* const* d_in, const int* in_sizes, int n_in,
                              void* d_out, int out_size, void* d_ws, size_t ws_size,
                              hipStream_t stream) {
  const float* obj = (const float*)d_in[0];
  const float* txt = (const float*)d_in[1];
  const float* mdl = (const float*)d_in[2];
  const int*   lab = (const int*)d_in[3];

  const int NB = in_sizes[1] / (4 * DD);   // 1280
  const int C  = in_sizes[2] / NB;          // 504

  float* ws = (float*)d_ws;
  size_t o = 0;
  float* objn = ws + o; o += (size_t)NB * 8 * DD;
  float* argn = ws + o; o += (size_t)NB * 3 * DD;
  float* t1n  = ws + o; o += (size_t)NB * DD;
  __hip_bfloat16* objb = (__hip_bfloat16*)(ws + o); o += (size_t)NB * 4 * DD;
  __hip_bfloat16* argb = (__hip_bfloat16*)(ws + o); o += ((size_t)NB * 3 * DD + 1) / 2;
  __hip_bfloat16* tenb = (__hip_bfloat16*)(ws + o); o += (size_t)NB * DD / 2;
  __hip_bfloat16* venb = (__hip_bfloat16*)(ws + o); o += (size_t)NB * DD / 2;
  float* diagmax = ws + o; o += (size_t)3 * NB;
  float* Ldiag = ws + o; o += (size_t)NB;
  float* zr = ws + o;
  float* sumexp = zr;                      // 3*NB
  float* rowsum = zr + 3 * NB;             // NB
  float* colsum = rowsum + NB;             // NB
  float* lossv  = colsum + NB;             // 1

  hipMemsetAsync(zr, 0, (size_t)(5 * NB + 1) * sizeof(float), stream);

  norm_rows<<<NB * 12, 64, 0, stream>>>(obj, txt, objn, argn, t1n, objb, argb, NB);
  wpg_gemm_256<<<dim3(NB * 8 / 256, NB * 3 / 256), 512, 0, stream>>>(argb, objb, sumexp);
  diag_teve<<<NB, 64, 0, stream>>>(argn, objn, t1n, diagmax, tenb, venb);
  ec_gemm_mfma<<<dim3(NB / 128, NB / 128), 256, 0, stream>>>(tenb, venb, rowsum, colsum, Ldiag);
  lossv_kernel<<<NB, 64, 0, stream>>>(mdl, lab, lossv, C);
  finalize_kernel<<<1, 256, 0, stream>>>(sumexp, diagmax, rowsum, colsum, Ldiag, lossv,
                                         (float*)d_out, NB);
}

// Round 4
// 209.502 us; speedup vs baseline: 1.1218x; 1.1218x over previous
//
#include <hip/hip_runtime.h>
#include <hip/hip_bf16.h>
#include <cstdint>
#include <cstddef>

#define DD 768
#define TSCALE 20.0f

typedef short bf16x8 __attribute__((ext_vector_type(8)));
typedef float f32x4 __attribute__((ext_vector_type(4)));

__device__ inline float wsum(float v){
  #pragma unroll
  for (int m = 1; m < 64; m <<= 1) v += __shfl_xor(v, m, 64);
  return v;
}
__device__ inline float wmax(float v){
  #pragma unroll
  for (int m = 1; m < 64; m <<= 1) v = fmaxf(v, __shfl_xor(v, m, 64));
  return v;
}

__device__ inline void gload_lds16(const void* g, void* l){
  __builtin_amdgcn_global_load_lds(
      (const __attribute__((address_space(1))) uint32_t*)g,
      (__attribute__((address_space(3))) uint32_t*)l, 16, 0, 0);
}

// Normalize rows: obj (8*NB), arg slots {0,2,3} (3*NB), text slot 1 (NB).
__global__ __launch_bounds__(64) void norm_rows(
    const float* __restrict__ obj, const float* __restrict__ txt,
    float* __restrict__ objn, float* __restrict__ argn, float* __restrict__ t1n,
    __hip_bfloat16* __restrict__ objb, __hip_bfloat16* __restrict__ argb, int NB)
{
  int row = blockIdx.x, lane = threadIdx.x;
  int NO = NB * 8, NA = NB * 3;
  const float* src; float* dst; __hip_bfloat16* bdst = nullptr;
  if (row < NO) {
    src = obj + (size_t)row * DD; dst = objn + (size_t)row * DD; bdst = objb + (size_t)row * DD;
  } else if (row < NO + NA) {
    int r = row - NO; int i = r / 3, j = r - i * 3; int s = (j == 0) ? 0 : (j + 1);
    src = txt + ((size_t)i * 4 + s) * DD; dst = argn + (size_t)r * DD; bdst = argb + (size_t)r * DD;
  } else {
    int i = row - NO - NA;
    src = txt + ((size_t)i * 4 + 1) * DD; dst = t1n + (size_t)i * DD;
  }
  float v[12]; float ss = 0.f;
  #pragma unroll
  for (int q = 0; q < 12; ++q){ v[q] = src[lane + q * 64]; ss += v[q] * v[q]; }
  ss = wsum(ss);
  float inv = 1.0f / fmaxf(sqrtf(ss), 1e-12f);
  #pragma unroll
  for (int q = 0; q < 12; ++q){
    float x = v[q] * inv;
    dst[lane + q * 64] = x;
    if (bdst) bdst[lane + q * 64] = __float2bfloat16(x);
  }
}

// ===================== wpg GEMM: 256x256 tile, BK=64, 8-phase, T2 swizzle ==========
// A = argb [3840, 768], B = objb [10240, 768] (row-major bf16, K-contig).
// Fused epilogue: sumexp[row] += sum_col exp(20*c - 20).
// LDS 128 KiB: [buf(2)][mat(2)][half(2)] of 16 KiB (128 rows x 128 B, linear store).
// T2: 16-B chunk index within a row XORed with (row&7) — applied to the GLOBAL
// source during staging (gload_lds dest must stay linear) and to the READ addr.
#define LDSOFF(buf, mat, half) (((buf) << 16) + ((mat) << 15) + ((half) << 14))

__global__ __launch_bounds__(512, 2) void wpg_gemm_256(
    const __hip_bfloat16* __restrict__ A, const __hip_bfloat16* __restrict__ B,
    float* __restrict__ sumexp)
{
  __shared__ char lds[131072];
  const int tid = threadIdx.x;
  const int lane = tid & 63, wid = tid >> 6;
  const int wr = wid >> 2, wc = wid & 3;          // 2 x 4 waves
  const int r = lane & 15, kg = lane >> 4;        // frag row / k-group

  const char* Abase = (const char*)A + (size_t)blockIdx.y * 256 * (DD * 2);
  const char* Bbase = (const char*)B + (size_t)blockIdx.x * 256 * (DD * 2);

  const int r0 = tid >> 3,        ch0 = (tid & 7) ^ (r0 & 7);
  const int r1 = (tid + 512) >> 3, ch1 = (tid & 7) ^ (r1 & 7);
  const int c0 = tid, c1 = tid + 512;

  auto STAGE = [&](const char* gbase, int buf, int mat, int half, int kt){
    gload_lds16(gbase + (size_t)(half * 128 + r0) * (DD * 2) + kt * 128 + ch0 * 16,
                lds + LDSOFF(buf, mat, half) + c0 * 16);
    gload_lds16(gbase + (size_t)(half * 128 + r1) * (DD * 2) + kt * 128 + ch1 * 16,
                lds + LDSOFF(buf, mat, half) + c1 * 16);
  };
  // A frag: row = mi*16 + r within half 'wr'; chunk = (kk*4+kg) ^ (r&7)
  auto LDA = [&](int buf, int mi, int kk)->bf16x8 {
    return *(const bf16x8*)(lds + LDSOFF(buf, 0, wr) + (mi * 16 + r) * 128 + (((kk * 4 + kg) ^ (r & 7)) * 16));
  };
  auto LDB = [&](int buf, int ni, int kk)->bf16x8 {
    return *(const bf16x8*)(lds + LDSOFF(buf, 1, wc >> 1) + ((wc & 1) * 64 + ni * 16 + r) * 128 + (((kk * 4 + kg) ^ (r & 7)) * 16));
  };

  f32x4 acc[8][4];
  #pragma unroll
  for (int i = 0; i < 8; ++i)
    #pragma unroll
    for (int j = 0; j < 4; ++j) acc[i][j] = (f32x4){0.f, 0.f, 0.f, 0.f};

  bf16x8 a[4][2], b0[2][2], b1[2][2];

  // Prologue: tile0 (full, buf0) + tile1 B halves (buf1).
  STAGE(Bbase, 0, 1, 0, 0); STAGE(Bbase, 0, 1, 1, 0);
  STAGE(Abase, 0, 0, 0, 0); STAGE(Abase, 0, 0, 1, 0);
  STAGE(Bbase, 1, 1, 0, 1); STAGE(Bbase, 1, 1, 1, 1);
  asm volatile("s_waitcnt vmcnt(4)" ::: "memory");
  __builtin_amdgcn_s_barrier();
  __builtin_amdgcn_sched_barrier(0);

  #define MFMA_(d, av, bv) d = __builtin_amdgcn_mfma_f32_16x16x32_bf16(av, bv, d, 0, 0, 0)

  for (int it = 0; it < 6; ++it){
    const int t1 = 2 * it + 1;
    const int t2 = (2 * it + 2 < 11) ? 2 * it + 2 : 11;
    const int t3 = (2 * it + 3 < 11) ? 2 * it + 3 : 11;

    // ---- P0: buf0, quad(mi0-3, ni0-1). stage A-h0(t1)->buf1
    #pragma unroll
    for (int mi = 0; mi < 4; ++mi){ a[mi][0] = LDA(0, mi, 0); a[mi][1] = LDA(0, mi, 1); }
    #pragma unroll
    for (int ni = 0; ni < 2; ++ni){ b0[ni][0] = LDB(0, ni, 0); b0[ni][1] = LDB(0, ni, 1); }
    STAGE(Abase, 1, 0, 0, t1);
    __builtin_amdgcn_s_barrier();
    __builtin_amdgcn_s_setprio(1);
    #pragma unroll
    for (int mi = 0; mi < 4; ++mi)
      #pragma unroll
      for (int ni = 0; ni < 2; ++ni){ MFMA_(acc[mi][ni], a[mi][0], b0[ni][0]); MFMA_(acc[mi][ni], a[mi][1], b0[ni][1]); }
    __builtin_amdgcn_s_setprio(0);
    __builtin_amdgcn_s_barrier();

    // ---- P1: buf0, quad(mi0-3, ni2-3). stage A-h1(t1)->buf1
    #pragma unroll
    for (int ni = 0; ni < 2; ++ni){ b1[ni][0] = LDB(0, 2 + ni, 0); b1[ni][1] = LDB(0, 2 + ni, 1); }
    STAGE(Abase, 1, 0, 1, t1);
    __builtin_amdgcn_s_barrier();
    __builtin_amdgcn_s_setprio(1);
    #pragma unroll
    for (int mi = 0; mi < 4; ++mi)
      #pragma unroll
      for (int ni = 0; ni < 2; ++ni){ MFMA_(acc[mi][2 + ni], a[mi][0], b1[ni][0]); MFMA_(acc[mi][2 + ni], a[mi][1], b1[ni][1]); }
    __builtin_amdgcn_s_setprio(0);
    __builtin_amdgcn_s_barrier();

    // ---- P2: buf0, quad(mi4-7, ni2-3). stage B-h0(t2)->buf0
    #pragma unroll
    for (int mi = 0; mi < 4; ++mi){ a[mi][0] = LDA(0, 4 + mi, 0); a[mi][1] = LDA(0, 4 + mi, 1); }
    STAGE(Bbase, 0, 1, 0, t2);
    __builtin_amdgcn_s_barrier();
    __builtin_amdgcn_s_setprio(1);
    #pragma unroll
    for (int mi = 0; mi < 4; ++mi)
      #pragma unroll
      for (int ni = 0; ni < 2; ++ni){ MFMA_(acc[4 + mi][2 + ni], a[mi][0], b1[ni][0]); MFMA_(acc[4 + mi][2 + ni], a[mi][1], b1[ni][1]); }
    __builtin_amdgcn_s_setprio(0);
    __builtin_amdgcn_s_barrier();

    // ---- P3: buf0, quad(mi4-7, ni0-1). stage B-h1(t2)->buf0. vmcnt gate for buf1 reads.
    STAGE(Bbase, 0, 1, 1, t2);
    __builtin_amdgcn_s_barrier();
    __builtin_amdgcn_s_setprio(1);
    #pragma unroll
    for (int mi = 0; mi < 4; ++mi)
      #pragma unroll
      for (int ni = 0; ni < 2; ++ni){ MFMA_(acc[4 + mi][ni], a[mi][0], b0[ni][0]); MFMA_(acc[4 + mi][ni], a[mi][1], b0[ni][1]); }
    __builtin_amdgcn_s_setprio(0);
    asm volatile("s_waitcnt vmcnt(4)" ::: "memory");
    __builtin_amdgcn_s_barrier();
    __builtin_amdgcn_sched_barrier(0);

    // ---- P4: buf1, quad(mi0-3, ni0-1). stage A-h0(t2)->buf0
    #pragma unroll
    for (int mi = 0; mi < 4; ++mi){ a[mi][0] = LDA(1, mi, 0); a[mi][1] = LDA(1, mi, 1); }
    #pragma unroll
    for (int ni = 0; ni < 2; ++ni){ b0[ni][0] = LDB(1, ni, 0); b0[ni][1] = LDB(1, ni, 1); }
    STAGE(Abase, 0, 0, 0, t2);
    __builtin_amdgcn_s_barrier();
    __builtin_amdgcn_s_setprio(1);
    #pragma unroll
    for (int mi = 0; mi < 4; ++mi)
      #pragma unroll
      for (int ni = 0; ni < 2; ++ni){ MFMA_(acc[mi][ni], a[mi][0], b0[ni][0]); MFMA_(acc[mi][ni], a[mi][1], b0[ni][1]); }
    __builtin_amdgcn_s_setprio(0);
    __builtin_amdgcn_s_barrier();

    // ---- P5: buf1, quad(mi0-3, ni2-3). stage A-h1(t2)->buf0
    #pragma unroll
    for (int ni = 0; ni < 2; ++ni){ b1[ni][0] = LDB(1, 2 + ni, 0); b1[ni][1] = LDB(1, 2 + ni, 1); }
    STAGE(Abase, 0, 0, 1, t2);
    __builtin_amdgcn_s_barrier();
    __builtin_amdgcn_s_setprio(1);
    #pragma unroll
    for (int mi = 0; mi < 4; ++mi)
      #pragma unroll
      for (int ni = 0; ni < 2; ++ni){ MFMA_(acc[mi][2 + ni], a[mi][0], b1[ni][0]); MFMA_(acc[mi][2 + ni], a[mi][1], b1[ni][1]); }
    __builtin_amdgcn_s_setprio(0);
    __builtin_amdgcn_s_barrier();

    // ---- P6: buf1, quad(mi4-7, ni2-3). stage B-h0(t3)->buf1
    #pragma unroll
    for (int mi = 0; mi < 4; ++mi){ a[mi][0] = LDA(1, 4 + mi, 0); a[mi][1] = LDA(1, 4 + mi, 1); }
    STAGE(Bbase, 1, 1, 0, t3);
    __builtin_amdgcn_s_barrier();
    __builtin_amdgcn_s_setprio(1);
    #pragma unroll
    for (int mi = 0; mi < 4; ++mi)
      #pragma unroll
      for (int ni = 0; ni < 2; ++ni){ MFMA_(acc[4 + mi][2 + ni], a[mi][0], b1[ni][0]); MFMA_(acc[4 + mi][2 + ni], a[mi][1], b1[ni][1]); }
    __builtin_amdgcn_s_setprio(0);
    __builtin_amdgcn_s_barrier();

    // ---- P7: buf1, quad(mi4-7, ni0-1). stage B-h1(t3)->buf1. vmcnt gate for next buf0 reads.
    STAGE(Bbase, 1, 1, 1, t3);
    __builtin_amdgcn_s_barrier();
    __builtin_amdgcn_s_setprio(1);
    #pragma unroll
    for (int mi = 0; mi < 4; ++mi)
      #pragma unroll
      for (int ni = 0; ni < 2; ++ni){ MFMA_(acc[4 + mi][ni], a[mi][0], b0[ni][0]); MFMA_(acc[4 + mi][ni], a[mi][1], b0[ni][1]); }
    __builtin_amdgcn_s_setprio(0);
    asm volatile("s_waitcnt vmcnt(4)" ::: "memory");
    __builtin_amdgcn_s_barrier();
    __builtin_amdgcn_sched_barrier(0);
  }

  // Epilogue: per-row sum of exp(20c-20). C layout: col = lane&15, row = kg*4 + reg.
  const int rowbase = blockIdx.y * 256 + wr * 128 + kg * 4;
  #pragma unroll
  for (int mi = 0; mi < 8; ++mi){
    #pragma unroll
    for (int rr = 0; rr < 4; ++rr){
      float s = 0.f;
      #pragma unroll
      for (int ni = 0; ni < 4; ++ni) s += expf(fmaf(acc[mi][ni][rr], TSCALE, -TSCALE));
      s += __shfl_xor(s, 1, 64); s += __shfl_xor(s, 2, 64);
      s += __shfl_xor(s, 4, 64); s += __shfl_xor(s, 8, 64);
      if (r == 0) atomicAdd(&sumexp[rowbase + mi * 16 + rr], s);
    }
  }
}

// =========== fused diag (exact fp32 argmax/mask) + te/ve assembly ===========
// One block per video i; the 8 obj rows cached in LDS (read once, used 3x + gather).
__global__ __launch_bounds__(64) void diag_teve(
    const float* __restrict__ argn, const float* __restrict__ objn, const float* __restrict__ t1n,
    float* __restrict__ diagmax,
    __hip_bfloat16* __restrict__ tenb, __hip_bfloat16* __restrict__ venb)
{
  __shared__ float so[8][DD];
  int i = blockIdx.x, lane = threadIdx.x;
  {
    const float4* src = (const float4*)(objn + (size_t)i * 8 * DD);
    float4* dst = (float4*)so;
    for (int c = lane; c < 8 * (DD / 4); c += 64) dst[c] = src[c];
  }
  __syncthreads();

  float te[12], ve[12];
  #pragma unroll
  for (int q = 0; q < 12; ++q){ te[q] = t1n[(size_t)i * DD + lane + q * 64]; ve[q] = 0.f; }

  for (int j = 0; j < 3; ++j){
    int rr = i * 3 + j;
    float a[12];
    #pragma unroll
    for (int q = 0; q < 12; ++q) a[q] = argn[(size_t)rr * DD + lane + q * 64];
    float best = -3.0e38f; int bi = 0;
    for (int k = 0; k < 8; ++k){
      float s = 0.f;
      #pragma unroll
      for (int q = 0; q < 12; ++q) s += a[q] * so[k][lane + q * 64];
      s = wsum(s);
      if (s > best){ best = s; bi = k; }   // strict > == first-index tie rule
    }
    float dm = best * TSCALE;
    if (lane == 0) diagmax[rr] = dm;
    if (dm > 1.0f){                         // uniform across wave (wsum broadcast)
      #pragma unroll
      for (int q = 0; q < 12; ++q){ te[q] += a[q]; ve[q] += so[bi][lane + q * 64]; }
    }
  }
  float ss = 0.f;
  #pragma unroll
  for (int q = 0; q < 12; ++q) ss += te[q] * te[q];
  ss = wsum(ss);
  float inv = 1.0f / fmaxf(sqrtf(ss), 1e-12f);
  #pragma unroll
  for (int q = 0; q < 12; ++q) tenb[(size_t)i * DD + lane + q * 64] = __float2bfloat16(te[q] * inv);
  ss = 0.f;
  #pragma unroll
  for (int q = 0; q < 12; ++q) ss += ve[q] * ve[q];
  ss = wsum(ss);
  inv = 1.0f / fmaxf(sqrtf(ss), 1e-12f);
  #pragma unroll
  for (int q = 0; q < 12; ++q) venb[(size_t)i * DD + lane + q * 64] = __float2bfloat16(ve[q] * inv);
}

// ec: A=tenb, B=venb [NB,768]; fused row/col exp-sums + diag capture (128^2 m97 structure).
__global__ __launch_bounds__(256) void ec_gemm_mfma(
    const __hip_bfloat16* __restrict__ A, const __hip_bfloat16* __restrict__ B,
    float* __restrict__ rowsum, float* __restrict__ colsum, float* __restrict__ Ldiag)
{
  __shared__ __hip_bfloat16 As[128 * 32];
  __shared__ __hip_bfloat16 Bs[128 * 32];
  int tid = threadIdx.x;
  int bx = blockIdx.x, by = blockIdx.y;
  int wid = tid >> 6, lane = tid & 63;
  int wr = wid >> 1, wc = wid & 1;

  f32x4 acc[4][4];
  #pragma unroll
  for (int i = 0; i < 4; ++i)
    #pragma unroll
    for (int j = 0; j < 4; ++j) acc[i][j] = (f32x4){0.f, 0.f, 0.f, 0.f};

  const char* Ab = (const char*)(A + (size_t)(by * 128) * DD);
  const char* Bb = (const char*)(B + (size_t)(bx * 128) * DD);
  int srow = tid >> 2;
  int scol = (tid & 3) * 16;
  char* AsB = (char*)As; char* BsB = (char*)Bs;
  int r = lane & 15, kg = (lane >> 4) * 8;

  for (int kb = 0; kb < DD * 2; kb += 64){
    gload_lds16(Ab + (size_t)srow * (DD*2) + kb + scol, AsB + tid * 16);
    gload_lds16(Ab + (size_t)(srow + 64) * (DD*2) + kb + scol, AsB + 4096 + tid * 16);
    gload_lds16(Bb + (size_t)srow * (DD*2) + kb + scol, BsB + tid * 16);
    gload_lds16(Bb + (size_t)(srow + 64) * (DD*2) + kb + scol, BsB + 4096 + tid * 16);
    __syncthreads();
    bf16x8 af[4], bfr[4];
    #pragma unroll
    for (int mi = 0; mi < 4; ++mi)
      af[mi] = *(const bf16x8*)&As[(wr * 64 + mi * 16 + r) * 32 + kg];
    #pragma unroll
    for (int ni = 0; ni < 4; ++ni)
      bfr[ni] = *(const bf16x8*)&Bs[(wc * 64 + ni * 16 + r) * 32 + kg];
    #pragma unroll
    for (int mi = 0; mi < 4; ++mi)
      #pragma unroll
      for (int ni = 0; ni < 4; ++ni)
        acc[mi][ni] = __builtin_amdgcn_mfma_f32_16x16x32_bf16(af[mi], bfr[ni], acc[mi][ni], 0, 0, 0);
    __syncthreads();
  }
  int rowbase = by * 128 + wr * 64 + ((lane >> 4) << 2);
  float colacc[4] = {0.f, 0.f, 0.f, 0.f};
  #pragma unroll
  for (int mi = 0; mi < 4; ++mi){
    #pragma unroll
    for (int rr = 0; rr < 4; ++rr){
      float s = 0.f;
      #pragma unroll
      for (int ni = 0; ni < 4; ++ni){
        float e = expf(fmaf(acc[mi][ni][rr], TSCALE, -TSCALE));
        s += e; colacc[ni] += e;
      }
      s += __shfl_xor(s, 1, 64); s += __shfl_xor(s, 2, 64);
      s += __shfl_xor(s, 4, 64); s += __shfl_xor(s, 8, 64);
      if ((lane & 15) == 0) atomicAdd(&rowsum[rowbase + mi * 16 + rr], s);
    }
  }
  #pragma unroll
  for (int ni = 0; ni < 4; ++ni){
    float c = colacc[ni];
    c += __shfl_xor(c, 16, 64); c += __shfl_xor(c, 32, 64);
    if (lane < 16) atomicAdd(&colsum[bx * 128 + wc * 64 + ni * 16 + lane], c);
  }
  if (bx == by){
    #pragma unroll
    for (int mi = 0; mi < 4; ++mi)
      #pragma unroll
      for (int ni = 0; ni < 4; ++ni)
        #pragma unroll
        for (int rr = 0; rr < 4; ++rr){
          int grow = wr * 64 + mi * 16 + ((lane >> 4) << 2) + rr;
          int gcol = wc * 64 + ni * 16 + (lane & 15);
          if (grow == gcol) Ldiag[by * 128 + grow] = acc[mi][ni][rr] * TSCALE;
        }
  }
}

__global__ __launch_bounds__(64) void lossv_kernel(
    const float* __restrict__ mdl, const int* __restrict__ lab,
    float* __restrict__ acc, int C)
{
  int row = blockIdx.x, lane = threadIdx.x;
  const float* x = mdl + (size_t)row * C;
  float mx = -3.0e38f;
  for (int c = lane; c < C; c += 64) mx = fmaxf(mx, x[c]);
  mx = wmax(mx);
  float s = 0.f;
  for (int c = lane; c < C; c += 64) s += expf(x[c] - mx);
  s = wsum(s);
  if (lane == 0) atomicAdd(acc, logf(s) + mx - x[lab[row]]);
}

__global__ __launch_bounds__(256) void finalize_kernel(
    const float* __restrict__ sumexp, const float* __restrict__ diagmax,
    const float* __restrict__ rowsum, const float* __restrict__ colsum,
    const float* __restrict__ Ldiag, const float* __restrict__ lossv,
    float* __restrict__ out, int NB)
{
  int tid = threadIdx.x;
  float p = 0.f;
  for (int r = tid; r < 3 * NB; r += 256) p += logf(sumexp[r]) + TSCALE - diagmax[r];
  p *= (0.3f / (3.0f * NB));
  float q = 0.f;
  for (int i2 = tid; i2 < NB; i2 += 256)
    q += (logf(rowsum[i2]) + TSCALE - Ldiag[i2]) + (logf(colsum[i2]) + TSCALE - Ldiag[i2]);
  p += q * (0.25f / NB);
  __shared__ float red[256];
  red[tid] = p; __syncthreads();
  for (int s = 128; s > 0; s >>= 1){ if (tid < s) red[tid] += red[tid + s]; __syncthreads(); }
  if (tid == 0) out[0] = red[0] + 0.2f * (lossv[0] / NB);
}

extern "C" void kernel_launch(void* const* d_in, const int* in_sizes, int n_in,
                              void* d_out, int out_size, void* d_ws, size_t ws_size,
                              hipStream_t stream) {
  const float* obj = (const float*)d_in[0];
  const float* txt = (const float*)d_in[1];
  const float* mdl = (const float*)d_in[2];
  const int*   lab = (const int*)d_in[3];

  const int NB = in_sizes[1] / (4 * DD);   // 1280
  const int C  = in_sizes[2] / NB;          // 504

  float* ws = (float*)d_ws;
  size_t o = 0;
  float* objn = ws + o; o += (size_t)NB * 8 * DD;
  float* argn = ws + o; o += (size_t)NB * 3 * DD;
  float* t1n  = ws + o; o += (size_t)NB * DD;
  __hip_bfloat16* objb = (__hip_bfloat16*)(ws + o); o += (size_t)NB * 4 * DD;
  __hip_bfloat16* argb = (__hip_bfloat16*)(ws + o); o += ((size_t)NB * 3 * DD + 1) / 2;
  __hip_bfloat16* tenb = (__hip_bfloat16*)(ws + o); o += (size_t)NB * DD / 2;
  __hip_bfloat16* venb = (__hip_bfloat16*)(ws + o); o += (size_t)NB * DD / 2;
  float* diagmax = ws + o; o += (size_t)3 * NB;
  float* Ldiag = ws + o; o += (size_t)NB;
  float* zr = ws + o;
  float* sumexp = zr;                      // 3*NB
  float* rowsum = zr + 3 * NB;             // NB
  float* colsum = rowsum + NB;             // NB
  float* lossv  = colsum + NB;             // 1

  hipMemsetAsync(zr, 0, (size_t)(5 * NB + 1) * sizeof(float), stream);

  norm_rows<<<NB * 12, 64, 0, stream>>>(obj, txt, objn, argn, t1n, objb, argb, NB);
  wpg_gemm_256<<<dim3(NB * 8 / 256, NB * 3 / 256), 512, 0, stream>>>(argb, objb, sumexp);
  diag_teve<<<NB, 64, 0, stream>>>(argn, objn, t1n, diagmax, tenb, venb);
  ec_gemm_mfma<<<dim3(NB / 128, NB / 128), 256, 0, stream>>>(tenb, venb, rowsum, colsum, Ldiag);
  lossv_kernel<<<NB, 64, 0, stream>>>(mdl, lab, lossv, C);
  finalize_kernel<<<1, 256, 0, stream>>>(sumexp, diagmax, rowsum, colsum, Ldiag, lossv,
                                         (float*)d_out, NB);
}

// Round 5
// 196.789 us; speedup vs baseline: 1.1942x; 1.0646x over previous
//
#include <hip/hip_runtime.h>
#include <hip/hip_bf16.h>
#include <cstdint>
#include <cstddef>

#define DD 768
#define TSCALE 20.0f

typedef short bf16x8 __attribute__((ext_vector_type(8)));
typedef float f32x4 __attribute__((ext_vector_type(4)));

__device__ inline float wsum(float v){
  #pragma unroll
  for (int m = 1; m < 64; m <<= 1) v += __shfl_xor(v, m, 64);
  return v;
}
__device__ inline float wmax(float v){
  #pragma unroll
  for (int m = 1; m < 64; m <<= 1) v = fmaxf(v, __shfl_xor(v, m, 64));
  return v;
}

__device__ inline void gload_lds16(const void* g, void* l){
  __builtin_amdgcn_global_load_lds(
      (const __attribute__((address_space(1))) uint32_t*)g,
      (__attribute__((address_space(3))) uint32_t*)l, 16, 0, 0);
}

__device__ inline void store_bf16x4(__hip_bfloat16* p, float4 x){
  __hip_bfloat16 t[4] = {__float2bfloat16(x.x), __float2bfloat16(x.y),
                         __float2bfloat16(x.z), __float2bfloat16(x.w)};
  *(ushort4*)p = *(const ushort4*)t;
}

// Normalize rows -> bf16 only. obj (8*NB rows) then arg slots {0,2,3} (3*NB rows).
// 256 threads = 4 waves, one row per wave, float4 loads (16B/lane).
__global__ __launch_bounds__(256) void norm_rows(
    const float* __restrict__ obj, const float* __restrict__ txt,
    __hip_bfloat16* __restrict__ objb, __hip_bfloat16* __restrict__ argb, int NB)
{
  int row = blockIdx.x * 4 + (threadIdx.x >> 6);
  int lane = threadIdx.x & 63;
  int NO = NB * 8;
  const float* src; __hip_bfloat16* bdst;
  if (row < NO) {
    src = obj + (size_t)row * DD; bdst = objb + (size_t)row * DD;
  } else {
    int r = row - NO; int i = r / 3, j = r - i * 3; int s = (j == 0) ? 0 : (j + 1);
    src = txt + ((size_t)i * 4 + s) * DD; bdst = argb + (size_t)r * DD;
  }
  float4 v[3]; float ss = 0.f;
  #pragma unroll
  for (int q = 0; q < 3; ++q){
    v[q] = ((const float4*)src)[lane + q * 64];
    ss += v[q].x * v[q].x + v[q].y * v[q].y + v[q].z * v[q].z + v[q].w * v[q].w;
  }
  ss = wsum(ss);
  float inv = 1.0f / fmaxf(sqrtf(ss), 1e-12f);
  #pragma unroll
  for (int q = 0; q < 3; ++q){
    float4 x = {v[q].x * inv, v[q].y * inv, v[q].z * inv, v[q].w * inv};
    store_bf16x4(bdst + lane * 4 + q * 256, x);
  }
}

// ===================== wpg GEMM: 256x256 tile, BK=64, 8-phase, T2 swizzle ==========
// A = argb [3840, 768], B = objb [10240, 768] (row-major bf16, K-contig).
// Fused epilogue: sumexp[row] += sum_col exp(20*c - 20).
// LDS 128 KiB: [buf(2)][mat(2)][half(2)] of 16 KiB (128 rows x 128 B, linear store).
// T2: 16-B chunk index XORed with (row&7), applied to GLOBAL src + LDS read addr.
// T1: XCD-chunked 1-D grid remap (5 bx per XCD) for L2-resident staging.
#define LDSOFF(buf, mat, half) (((buf) << 16) + ((mat) << 15) + ((half) << 14))

__global__ __launch_bounds__(512, 2) void wpg_gemm_256(
    const __hip_bfloat16* __restrict__ A, const __hip_bfloat16* __restrict__ B,
    float* __restrict__ sumexp, int nxb)
{
  __shared__ char lds[131072];
  const int tid = threadIdx.x;
  const int lane = tid & 63, wid = tid >> 6;
  const int wr = wid >> 2, wc = wid & 3;          // 2 x 4 waves
  const int r = lane & 15, kg = lane >> 4;        // frag row / k-group

  int g = blockIdx.x, bx, by;
  if ((nxb & 7) == 0){
    int cpx = nxb >> 3;
    int xcd = g & 7, idx = g >> 3;
    bx = xcd * cpx + idx % cpx;
    by = idx / cpx;
  } else { bx = g % nxb; by = g / nxb; }

  const char* Abase = (const char*)A + (size_t)by * 256 * (DD * 2);
  const char* Bbase = (const char*)B + (size_t)bx * 256 * (DD * 2);

  const int r0 = tid >> 3,         ch0 = (tid & 7) ^ (r0 & 7);
  const int r1 = (tid + 512) >> 3, ch1 = (tid & 7) ^ (r1 & 7);
  const int c0 = tid, c1 = tid + 512;

  auto STAGE = [&](const char* gbase, int buf, int mat, int half, int kt){
    gload_lds16(gbase + (size_t)(half * 128 + r0) * (DD * 2) + kt * 128 + ch0 * 16,
                lds + LDSOFF(buf, mat, half) + c0 * 16);
    gload_lds16(gbase + (size_t)(half * 128 + r1) * (DD * 2) + kt * 128 + ch1 * 16,
                lds + LDSOFF(buf, mat, half) + c1 * 16);
  };
  auto LDA = [&](int buf, int mi, int kk)->bf16x8 {
    return *(const bf16x8*)(lds + LDSOFF(buf, 0, wr) + (mi * 16 + r) * 128 + (((kk * 4 + kg) ^ (r & 7)) * 16));
  };
  auto LDB = [&](int buf, int ni, int kk)->bf16x8 {
    return *(const bf16x8*)(lds + LDSOFF(buf, 1, wc >> 1) + ((wc & 1) * 64 + ni * 16 + r) * 128 + (((kk * 4 + kg) ^ (r & 7)) * 16));
  };

  f32x4 acc[8][4];
  #pragma unroll
  for (int i = 0; i < 8; ++i)
    #pragma unroll
    for (int j = 0; j < 4; ++j) acc[i][j] = (f32x4){0.f, 0.f, 0.f, 0.f};

  bf16x8 a[4][2], b0[2][2], b1[2][2];

  // Prologue: tile0 (full, buf0) + tile1 B halves (buf1).
  STAGE(Bbase, 0, 1, 0, 0); STAGE(Bbase, 0, 1, 1, 0);
  STAGE(Abase, 0, 0, 0, 0); STAGE(Abase, 0, 0, 1, 0);
  STAGE(Bbase, 1, 1, 0, 1); STAGE(Bbase, 1, 1, 1, 1);
  asm volatile("s_waitcnt vmcnt(4)" ::: "memory");
  __builtin_amdgcn_s_barrier();
  __builtin_amdgcn_sched_barrier(0);

  #define MFMA_(d, av, bv) d = __builtin_amdgcn_mfma_f32_16x16x32_bf16(av, bv, d, 0, 0, 0)

  for (int it = 0; it < 6; ++it){
    const int t1 = 2 * it + 1;
    const int t2 = (2 * it + 2 < 11) ? 2 * it + 2 : 11;
    const int t3 = (2 * it + 3 < 11) ? 2 * it + 3 : 11;

    // ---- P0: buf0, quad(mi0-3, ni0-1). stage A-h0(t1)->buf1
    #pragma unroll
    for (int mi = 0; mi < 4; ++mi){ a[mi][0] = LDA(0, mi, 0); a[mi][1] = LDA(0, mi, 1); }
    #pragma unroll
    for (int ni = 0; ni < 2; ++ni){ b0[ni][0] = LDB(0, ni, 0); b0[ni][1] = LDB(0, ni, 1); }
    STAGE(Abase, 1, 0, 0, t1);
    __builtin_amdgcn_s_barrier();
    __builtin_amdgcn_s_setprio(1);
    #pragma unroll
    for (int mi = 0; mi < 4; ++mi)
      #pragma unroll
      for (int ni = 0; ni < 2; ++ni){ MFMA_(acc[mi][ni], a[mi][0], b0[ni][0]); MFMA_(acc[mi][ni], a[mi][1], b0[ni][1]); }
    __builtin_amdgcn_s_setprio(0);
    __builtin_amdgcn_s_barrier();

    // ---- P1: buf0, quad(mi0-3, ni2-3). stage A-h1(t1)->buf1
    #pragma unroll
    for (int ni = 0; ni < 2; ++ni){ b1[ni][0] = LDB(0, 2 + ni, 0); b1[ni][1] = LDB(0, 2 + ni, 1); }
    STAGE(Abase, 1, 0, 1, t1);
    __builtin_amdgcn_s_barrier();
    __builtin_amdgcn_s_setprio(1);
    #pragma unroll
    for (int mi = 0; mi < 4; ++mi)
      #pragma unroll
      for (int ni = 0; ni < 2; ++ni){ MFMA_(acc[mi][2 + ni], a[mi][0], b1[ni][0]); MFMA_(acc[mi][2 + ni], a[mi][1], b1[ni][1]); }
    __builtin_amdgcn_s_setprio(0);
    __builtin_amdgcn_s_barrier();

    // ---- P2: buf0, quad(mi4-7, ni2-3). stage B-h0(t2)->buf0
    #pragma unroll
    for (int mi = 0; mi < 4; ++mi){ a[mi][0] = LDA(0, 4 + mi, 0); a[mi][1] = LDA(0, 4 + mi, 1); }
    STAGE(Bbase, 0, 1, 0, t2);
    __builtin_amdgcn_s_barrier();
    __builtin_amdgcn_s_setprio(1);
    #pragma unroll
    for (int mi = 0; mi < 4; ++mi)
      #pragma unroll
      for (int ni = 0; ni < 2; ++ni){ MFMA_(acc[4 + mi][2 + ni], a[mi][0], b1[ni][0]); MFMA_(acc[4 + mi][2 + ni], a[mi][1], b1[ni][1]); }
    __builtin_amdgcn_s_setprio(0);
    __builtin_amdgcn_s_barrier();

    // ---- P3: buf0, quad(mi4-7, ni0-1). stage B-h1(t2)->buf0. vmcnt gate for buf1 reads.
    STAGE(Bbase, 0, 1, 1, t2);
    __builtin_amdgcn_s_barrier();
    __builtin_amdgcn_s_setprio(1);
    #pragma unroll
    for (int mi = 0; mi < 4; ++mi)
      #pragma unroll
      for (int ni = 0; ni < 2; ++ni){ MFMA_(acc[4 + mi][ni], a[mi][0], b0[ni][0]); MFMA_(acc[4 + mi][ni], a[mi][1], b0[ni][1]); }
    __builtin_amdgcn_s_setprio(0);
    asm volatile("s_waitcnt vmcnt(4)" ::: "memory");
    __builtin_amdgcn_s_barrier();
    __builtin_amdgcn_sched_barrier(0);

    // ---- P4: buf1, quad(mi0-3, ni0-1). stage A-h0(t2)->buf0
    #pragma unroll
    for (int mi = 0; mi < 4; ++mi){ a[mi][0] = LDA(1, mi, 0); a[mi][1] = LDA(1, mi, 1); }
    #pragma unroll
    for (int ni = 0; ni < 2; ++ni){ b0[ni][0] = LDB(1, ni, 0); b0[ni][1] = LDB(1, ni, 1); }
    STAGE(Abase, 0, 0, 0, t2);
    __builtin_amdgcn_s_barrier();
    __builtin_amdgcn_s_setprio(1);
    #pragma unroll
    for (int mi = 0; mi < 4; ++mi)
      #pragma unroll
      for (int ni = 0; ni < 2; ++ni){ MFMA_(acc[mi][ni], a[mi][0], b0[ni][0]); MFMA_(acc[mi][ni], a[mi][1], b0[ni][1]); }
    __builtin_amdgcn_s_setprio(0);
    __builtin_amdgcn_s_barrier();

    // ---- P5: buf1, quad(mi0-3, ni2-3). stage A-h1(t2)->buf0
    #pragma unroll
    for (int ni = 0; ni < 2; ++ni){ b1[ni][0] = LDB(1, 2 + ni, 0); b1[ni][1] = LDB(1, 2 + ni, 1); }
    STAGE(Abase, 0, 0, 1, t2);
    __builtin_amdgcn_s_barrier();
    __builtin_amdgcn_s_setprio(1);
    #pragma unroll
    for (int mi = 0; mi < 4; ++mi)
      #pragma unroll
      for (int ni = 0; ni < 2; ++ni){ MFMA_(acc[mi][2 + ni], a[mi][0], b1[ni][0]); MFMA_(acc[mi][2 + ni], a[mi][1], b1[ni][1]); }
    __builtin_amdgcn_s_setprio(0);
    __builtin_amdgcn_s_barrier();

    // ---- P6: buf1, quad(mi4-7, ni2-3). stage B-h0(t3)->buf1
    #pragma unroll
    for (int mi = 0; mi < 4; ++mi){ a[mi][0] = LDA(1, 4 + mi, 0); a[mi][1] = LDA(1, 4 + mi, 1); }
    STAGE(Bbase, 1, 1, 0, t3);
    __builtin_amdgcn_s_barrier();
    __builtin_amdgcn_s_setprio(1);
    #pragma unroll
    for (int mi = 0; mi < 4; ++mi)
      #pragma unroll
      for (int ni = 0; ni < 2; ++ni){ MFMA_(acc[4 + mi][2 + ni], a[mi][0], b1[ni][0]); MFMA_(acc[4 + mi][2 + ni], a[mi][1], b1[ni][1]); }
    __builtin_amdgcn_s_setprio(0);
    __builtin_amdgcn_s_barrier();

    // ---- P7: buf1, quad(mi4-7, ni0-1). stage B-h1(t3)->buf1. vmcnt gate for next buf0 reads.
    STAGE(Bbase, 1, 1, 1, t3);
    __builtin_amdgcn_s_barrier();
    __builtin_amdgcn_s_setprio(1);
    #pragma unroll
    for (int mi = 0; mi < 4; ++mi)
      #pragma unroll
      for (int ni = 0; ni < 2; ++ni){ MFMA_(acc[4 + mi][ni], a[mi][0], b0[ni][0]); MFMA_(acc[4 + mi][ni], a[mi][1], b0[ni][1]); }
    __builtin_amdgcn_s_setprio(0);
    asm volatile("s_waitcnt vmcnt(4)" ::: "memory");
    __builtin_amdgcn_s_barrier();
    __builtin_amdgcn_sched_barrier(0);
  }

  // Epilogue: per-row sum of exp(20c-20). C layout: col = lane&15, row = kg*4 + reg.
  const int rowbase = by * 256 + wr * 128 + kg * 4;
  #pragma unroll
  for (int mi = 0; mi < 8; ++mi){
    #pragma unroll
    for (int rr = 0; rr < 4; ++rr){
      float s = 0.f;
      #pragma unroll
      for (int ni = 0; ni < 4; ++ni) s += expf(fmaf(acc[mi][ni][rr], TSCALE, -TSCALE));
      s += __shfl_xor(s, 1, 64); s += __shfl_xor(s, 2, 64);
      s += __shfl_xor(s, 4, 64); s += __shfl_xor(s, 8, 64);
      if (r == 0) atomicAdd(&sumexp[rowbase + mi * 16 + rr], s);
    }
  }
}

// =========== fused diag (exact fp32 argmax/mask) + te/ve from RAW inputs ===========
// One 64-thread block per video i. Normalizes the 8 obj rows + 3 arg slots + slot1
// in-kernel (fp32, same wsum tree), so no fp32 normalized arrays are materialized.
__global__ __launch_bounds__(64) void diag_teve(
    const float* __restrict__ obj, const float* __restrict__ txt,
    float* __restrict__ diagmax,
    __hip_bfloat16* __restrict__ tenb, __hip_bfloat16* __restrict__ venb)
{
  __shared__ float so[8][DD];
  int i = blockIdx.x, lane = threadIdx.x;
  const float* ob = obj + (size_t)i * 8 * DD;
  for (int k = 0; k < 8; ++k){
    float4 v[3]; float ss = 0.f;
    #pragma unroll
    for (int q = 0; q < 3; ++q){
      v[q] = ((const float4*)(ob + k * DD))[lane + q * 64];
      ss += v[q].x * v[q].x + v[q].y * v[q].y + v[q].z * v[q].z + v[q].w * v[q].w;
    }
    ss = wsum(ss);
    float inv = 1.0f / fmaxf(sqrtf(ss), 1e-12f);
    #pragma unroll
    for (int q = 0; q < 3; ++q){
      float4 x = {v[q].x * inv, v[q].y * inv, v[q].z * inv, v[q].w * inv};
      ((float4*)&so[k][0])[lane + q * 64] = x;
    }
  }
  __syncthreads();

  // te starts as normalized text slot 1
  float4 te[3], ve[3];
  {
    const float* t1 = txt + ((size_t)i * 4 + 1) * DD;
    float ss = 0.f;
    #pragma unroll
    for (int q = 0; q < 3; ++q){
      te[q] = ((const float4*)t1)[lane + q * 64];
      ss += te[q].x * te[q].x + te[q].y * te[q].y + te[q].z * te[q].z + te[q].w * te[q].w;
    }
    ss = wsum(ss);
    float inv = 1.0f / fmaxf(sqrtf(ss), 1e-12f);
    #pragma unroll
    for (int q = 0; q < 3; ++q){
      te[q].x *= inv; te[q].y *= inv; te[q].z *= inv; te[q].w *= inv;
      ve[q] = (float4){0.f, 0.f, 0.f, 0.f};
    }
  }

  for (int j = 0; j < 3; ++j){
    int rr = i * 3 + j;
    int s4 = (j == 0) ? 0 : (j + 1);
    const float* ap = txt + ((size_t)i * 4 + s4) * DD;
    float4 a[3]; float ss = 0.f;
    #pragma unroll
    for (int q = 0; q < 3; ++q){
      a[q] = ((const float4*)ap)[lane + q * 64];
      ss += a[q].x * a[q].x + a[q].y * a[q].y + a[q].z * a[q].z + a[q].w * a[q].w;
    }
    ss = wsum(ss);
    float inv = 1.0f / fmaxf(sqrtf(ss), 1e-12f);
    #pragma unroll
    for (int q = 0; q < 3; ++q){ a[q].x *= inv; a[q].y *= inv; a[q].z *= inv; a[q].w *= inv; }

    float best = -3.0e38f; int bi = 0;
    for (int k = 0; k < 8; ++k){
      float s = 0.f;
      #pragma unroll
      for (int q = 0; q < 3; ++q){
        float4 w = ((const float4*)&so[k][0])[lane + q * 64];
        s += a[q].x * w.x + a[q].y * w.y + a[q].z * w.z + a[q].w * w.w;
      }
      s = wsum(s);
      if (s > best){ best = s; bi = k; }   // strict > == first-index tie rule
    }
    float dm = best * TSCALE;
    if (lane == 0) diagmax[rr] = dm;
    if (dm > 1.0f){                         // uniform across wave (wsum broadcast)
      #pragma unroll
      for (int q = 0; q < 3; ++q){
        float4 w = ((const float4*)&so[bi][0])[lane + q * 64];
        te[q].x += a[q].x; te[q].y += a[q].y; te[q].z += a[q].z; te[q].w += a[q].w;
        ve[q].x += w.x;    ve[q].y += w.y;    ve[q].z += w.z;    ve[q].w += w.w;
      }
    }
  }
  float ss = 0.f;
  #pragma unroll
  for (int q = 0; q < 3; ++q)
    ss += te[q].x * te[q].x + te[q].y * te[q].y + te[q].z * te[q].z + te[q].w * te[q].w;
  ss = wsum(ss);
  float inv = 1.0f / fmaxf(sqrtf(ss), 1e-12f);
  #pragma unroll
  for (int q = 0; q < 3; ++q){
    float4 x = {te[q].x * inv, te[q].y * inv, te[q].z * inv, te[q].w * inv};
    store_bf16x4(tenb + (size_t)i * DD + lane * 4 + q * 256, x);
  }
  ss = 0.f;
  #pragma unroll
  for (int q = 0; q < 3; ++q)
    ss += ve[q].x * ve[q].x + ve[q].y * ve[q].y + ve[q].z * ve[q].z + ve[q].w * ve[q].w;
  ss = wsum(ss);
  inv = 1.0f / fmaxf(sqrtf(ss), 1e-12f);
  #pragma unroll
  for (int q = 0; q < 3; ++q){
    float4 x = {ve[q].x * inv, ve[q].y * inv, ve[q].z * inv, ve[q].w * inv};
    store_bf16x4(venb + (size_t)i * DD + lane * 4 + q * 256, x);
  }
}

// ec: A=tenb, B=venb [NB,768]; fused row/col exp-sums + diag capture (128^2 m97 structure).
__global__ __launch_bounds__(256) void ec_gemm_mfma(
    const __hip_bfloat16* __restrict__ A, const __hip_bfloat16* __restrict__ B,
    float* __restrict__ rowsum, float* __restrict__ colsum, float* __restrict__ Ldiag)
{
  __shared__ __hip_bfloat16 As[128 * 32];
  __shared__ __hip_bfloat16 Bs[128 * 32];
  int tid = threadIdx.x;
  int bx = blockIdx.x, by = blockIdx.y;
  int wid = tid >> 6, lane = tid & 63;
  int wr = wid >> 1, wc = wid & 1;

  f32x4 acc[4][4];
  #pragma unroll
  for (int i = 0; i < 4; ++i)
    #pragma unroll
    for (int j = 0; j < 4; ++j) acc[i][j] = (f32x4){0.f, 0.f, 0.f, 0.f};

  const char* Ab = (const char*)(A + (size_t)(by * 128) * DD);
  const char* Bb = (const char*)(B + (size_t)(bx * 128) * DD);
  int srow = tid >> 2;
  int scol = (tid & 3) * 16;
  char* AsB = (char*)As; char* BsB = (char*)Bs;
  int r = lane & 15, kg = (lane >> 4) * 8;

  for (int kb = 0; kb < DD * 2; kb += 64){
    gload_lds16(Ab + (size_t)srow * (DD*2) + kb + scol, AsB + tid * 16);
    gload_lds16(Ab + (size_t)(srow + 64) * (DD*2) + kb + scol, AsB + 4096 + tid * 16);
    gload_lds16(Bb + (size_t)srow * (DD*2) + kb + scol, BsB + tid * 16);
    gload_lds16(Bb + (size_t)(srow + 64) * (DD*2) + kb + scol, BsB + 4096 + tid * 16);
    __syncthreads();
    bf16x8 af[4], bfr[4];
    #pragma unroll
    for (int mi = 0; mi < 4; ++mi)
      af[mi] = *(const bf16x8*)&As[(wr * 64 + mi * 16 + r) * 32 + kg];
    #pragma unroll
    for (int ni = 0; ni < 4; ++ni)
      bfr[ni] = *(const bf16x8*)&Bs[(wc * 64 + ni * 16 + r) * 32 + kg];
    #pragma unroll
    for (int mi = 0; mi < 4; ++mi)
      #pragma unroll
      for (int ni = 0; ni < 4; ++ni)
        acc[mi][ni] = __builtin_amdgcn_mfma_f32_16x16x32_bf16(af[mi], bfr[ni], acc[mi][ni], 0, 0, 0);
    __syncthreads();
  }
  int rowbase = by * 128 + wr * 64 + ((lane >> 4) << 2);
  float colacc[4] = {0.f, 0.f, 0.f, 0.f};
  #pragma unroll
  for (int mi = 0; mi < 4; ++mi){
    #pragma unroll
    for (int rr = 0; rr < 4; ++rr){
      float s = 0.f;
      #pragma unroll
      for (int ni = 0; ni < 4; ++ni){
        float e = expf(fmaf(acc[mi][ni][rr], TSCALE, -TSCALE));
        s += e; colacc[ni] += e;
      }
      s += __shfl_xor(s, 1, 64); s += __shfl_xor(s, 2, 64);
      s += __shfl_xor(s, 4, 64); s += __shfl_xor(s, 8, 64);
      if ((lane & 15) == 0) atomicAdd(&rowsum[rowbase + mi * 16 + rr], s);
    }
  }
  #pragma unroll
  for (int ni = 0; ni < 4; ++ni){
    float c = colacc[ni];
    c += __shfl_xor(c, 16, 64); c += __shfl_xor(c, 32, 64);
    if (lane < 16) atomicAdd(&colsum[bx * 128 + wc * 64 + ni * 16 + lane], c);
  }
  if (bx == by){
    #pragma unroll
    for (int mi = 0; mi < 4; ++mi)
      #pragma unroll
      for (int ni = 0; ni < 4; ++ni)
        #pragma unroll
        for (int rr = 0; rr < 4; ++rr){
          int grow = wr * 64 + mi * 16 + ((lane >> 4) << 2) + rr;
          int gcol = wc * 64 + ni * 16 + (lane & 15);
          if (grow == gcol) Ldiag[by * 128 + grow] = acc[mi][ni][rr] * TSCALE;
        }
  }
}

__global__ __launch_bounds__(64) void lossv_kernel(
    const float* __restrict__ mdl, const int* __restrict__ lab,
    float* __restrict__ acc, int C)
{
  int row = blockIdx.x, lane = threadIdx.x;
  const float* x = mdl + (size_t)row * C;
  float mx = -3.0e38f;
  for (int c = lane; c < C; c += 64) mx = fmaxf(mx, x[c]);
  mx = wmax(mx);
  float s = 0.f;
  for (int c = lane; c < C; c += 64) s += expf(x[c] - mx);
  s = wsum(s);
  if (lane == 0) atomicAdd(acc, logf(s) + mx - x[lab[row]]);
}

__global__ __launch_bounds__(256) void finalize_kernel(
    const float* __restrict__ sumexp, const float* __restrict__ diagmax,
    const float* __restrict__ rowsum, const float* __restrict__ colsum,
    const float* __restrict__ Ldiag, const float* __restrict__ lossv,
    float* __restrict__ out, int NB)
{
  int tid = threadIdx.x;
  float p = 0.f;
  for (int r = tid; r < 3 * NB; r += 256) p += logf(sumexp[r]) + TSCALE - diagmax[r];
  p *= (0.3f / (3.0f * NB));
  float q = 0.f;
  for (int i2 = tid; i2 < NB; i2 += 256)
    q += (logf(rowsum[i2]) + TSCALE - Ldiag[i2]) + (logf(colsum[i2]) + TSCALE - Ldiag[i2]);
  p += q * (0.25f / NB);
  __shared__ float red[256];
  red[tid] = p; __syncthreads();
  for (int s = 128; s > 0; s >>= 1){ if (tid < s) red[tid] += red[tid + s]; __syncthreads(); }
  if (tid == 0) out[0] = red[0] + 0.2f * (lossv[0] / NB);
}

extern "C" void kernel_launch(void* const* d_in, const int* in_sizes, int n_in,
                              void* d_out, int out_size, void* d_ws, size_t ws_size,
                              hipStream_t stream) {
  const float* obj = (const float*)d_in[0];
  const float* txt = (const float*)d_in[1];
  const float* mdl = (const float*)d_in[2];
  const int*   lab = (const int*)d_in[3];

  const int NB = in_sizes[1] / (4 * DD);   // 1280
  const int C  = in_sizes[2] / NB;          // 504

  float* ws = (float*)d_ws;
  size_t o = 0;
  __hip_bfloat16* objb = (__hip_bfloat16*)(ws + o); o += (size_t)NB * 4 * DD;      // 8*NB rows bf16
  __hip_bfloat16* argb = (__hip_bfloat16*)(ws + o); o += (size_t)NB * 3 * DD / 2;  // 3*NB rows bf16
  __hip_bfloat16* tenb = (__hip_bfloat16*)(ws + o); o += (size_t)NB * DD / 2;
  __hip_bfloat16* venb = (__hip_bfloat16*)(ws + o); o += (size_t)NB * DD / 2;
  float* diagmax = ws + o; o += (size_t)3 * NB;
  float* Ldiag = ws + o; o += (size_t)NB;
  float* zr = ws + o;
  float* sumexp = zr;                      // 3*NB
  float* rowsum = zr + 3 * NB;             // NB
  float* colsum = rowsum + NB;             // NB
  float* lossv  = colsum + NB;             // 1

  hipMemsetAsync(zr, 0, (size_t)(5 * NB + 1) * sizeof(float), stream);

  norm_rows<<<NB * 11 / 4, 256, 0, stream>>>(obj, txt, objb, argb, NB);
  const int nxb = NB * 8 / 256, nyb = NB * 3 / 256;
  wpg_gemm_256<<<nxb * nyb, 512, 0, stream>>>(argb, objb, sumexp, nxb);
  diag_teve<<<NB, 64, 0, stream>>>(obj, txt, diagmax, tenb, venb);
  ec_gemm_mfma<<<dim3(NB / 128, NB / 128), 256, 0, stream>>>(tenb, venb, rowsum, colsum, Ldiag);
  lossv_kernel<<<NB, 64, 0, stream>>>(mdl, lab, lossv, C);
  finalize_kernel<<<1, 256, 0, stream>>>(sumexp, diagmax, rowsum, colsum, Ldiag, lossv,
                                         (float*)d_out, NB);
}